// Round 13
// baseline (333.537 us; speedup 1.0000x reference)
//
#include <hip/hip_runtime.h>
#include <math.h>

// Problem constants
#define NROWS 32768   // B*H*W
#define KCB   1024
#define DDIM  256
#define NHALF 16384

// Output offsets (floats)
#define O_LOSS 0
#define O_Q    1
#define O_PERP 8388609
#define O_ENC  8388610
#define O_NCNT 41943042
#define O_EMAW 41944066
#define O_EMB  42206210

// E-region scratch (floats rel. outE; region = 33,554,432 floats):
//   XS3   @ 2          : bf16 [32768][768] (hi|mid|lo) = 12,582,912 floats (16B-aligned)
//   Sslot @ 12582914   : fp32 [16384][1024] nd values = 16,777,216 floats -> ends 29,360,130
//   softT1 aliases XS3 base (written after refine); P partials alias Sslot head.
#define E_XS3   2
#define E_S     12582914

// Workspace offsets (floats)
#define W_WSQ  0        // 1024
#define W_XSQ  1024     // 32768
#define W_IDX  33792    // 32768 (int)
#define W_COL  66560    // 1024
#define W_HCNT 67584    // 1024
#define W_BENT 68608    // 8192 (h0: 256, h1: 4096 -> 4352 used)
#define W_NCNT 76800    // 1024
#define W_T2I  77824    // 65536 (int)
#define W_WB   143360   // 1024*256 ushorts = 131072 floats (w_hi only)
#define W_MROW 274432   // 16384 (h1 only)
#define W_IROW 307200   // 16384 (h1 only)

typedef __attribute__((ext_vector_type(8))) short bf16x8;
typedef __attribute__((ext_vector_type(4))) float f32x4;

#define GLOAD_LDS16(g, l) __builtin_amdgcn_global_load_lds( \
    (const __attribute__((address_space(1))) unsigned int*)(g), \
    (__attribute__((address_space(3))) unsigned int*)(l), 16, 0, 0)

__device__ __forceinline__ float wred_sum(float v) {
#pragma unroll
  for (int off = 32; off > 0; off >>= 1) v += __shfl_xor(v, off);
  return v;
}
__device__ __forceinline__ ushort f2bf(float f) {
  union { float f; unsigned u; } c; c.f = f;
  unsigned u = c.u;
  return (ushort)((u + 0x7fffu + ((u >> 16) & 1u)) >> 16);  // RNE
}
__device__ __forceinline__ float bf2f(ushort h) {
  union { unsigned u; float f; } c; c.u = ((unsigned)h) << 16;
  return c.f;
}

// ---------------- init ----------------
__global__ void k_init(float* __restrict__ hcnt, float* __restrict__ colsum) {
  int i = blockIdx.x * 256 + threadIdx.x;
  if (i < 1024) { hcnt[i] = 0.f; colsum[i] = 0.f; }
}

// ---------------- w -> wsq + WB [k][256] = w_hi ----------------
__global__ void k_wsplit(const float* __restrict__ w, float* __restrict__ wsq,
                         ushort* __restrict__ WB) {
  int t = threadIdx.x;
  int lane = t & 63, wv = t >> 6;
  int k = blockIdx.x * 4 + wv;
  int d0 = lane * 4;
  float4 v = *(const float4*)&w[(size_t)k * DDIM + d0];
  float s = v.x * v.x + v.y * v.y + v.z * v.z + v.w * v.w;
  s = wred_sum(s);
  if (lane == 0) wsq[k] = s;
  float vv[4] = {v.x, v.y, v.z, v.w};
  union { ushort u[4]; uint2 q; } hh;
#pragma unroll
  for (int q = 0; q < 4; ++q) hh.u[q] = f2bf(vv[q]);
  *(uint2*)&WB[(size_t)k * 256 + d0] = hh.q;
}

// ---------------- x -> XS3 (3-way bf16 split) + xsq ----------------
__global__ __launch_bounds__(256) void k_xsplit(const float* __restrict__ x,
                                                ushort* __restrict__ XS3,
                                                float* __restrict__ xsq) {
  __shared__ __align__(16) ushort sl[32 * 776];
  __shared__ float sq[32 * 9];
  int t = threadIdx.x;
  int b = blockIdx.x >> 5, mt = blockIdx.x & 31;
  int m0 = mt * 32, mloc = t & 31, dgrp = t >> 5;
  const float* xb = x + (size_t)b * DDIM * 1024 + m0 + mloc;
  float s = 0.f;
#pragma unroll
  for (int jj = 0; jj < 8; ++jj) {
    int d0 = dgrp * 32 + jj * 4;
    float vv[4];
#pragma unroll
    for (int q = 0; q < 4; ++q) vv[q] = xb[(size_t)(d0 + q) * 1024];
    union { ushort u[4]; uint2 q; } hh, mi, lo;
#pragma unroll
    for (int q = 0; q < 4; ++q) {
      float v = vv[q];
      ushort h = f2bf(v);
      float r1 = v - bf2f(h);
      ushort m_ = f2bf(r1);
      float r2 = r1 - bf2f(m_);
      hh.u[q] = h; mi.u[q] = m_; lo.u[q] = f2bf(r2);
      s = fmaf(v, v, s);
    }
    int base = mloc * 776;
    *(uint2*)&sl[base + d0] = hh.q;
    *(uint2*)&sl[base + 256 + d0] = mi.q;
    *(uint2*)&sl[base + 512 + d0] = lo.q;
  }
  sq[mloc * 9 + dgrp] = s;
  __syncthreads();
  if (t < 32) {
    float ss = 0.f;
#pragma unroll
    for (int gq = 0; gq < 8; ++gq) ss += sq[t * 9 + gq];
    xsq[b * 1024 + m0 + t] = ss;
  }
  ushort* dst = XS3 + (size_t)(b * 1024 + m0) * 768;
#pragma unroll
  for (int p = 0; p < 12; ++p) {
    int idx = p * 256 + t;
    int row = idx / 96;
    int co = idx - row * 96;
    *(uint4*)&dst[(size_t)row * 768 + co * 8] = *(uint4*)&sl[row * 776 + co * 8];
  }
}

// ---------------- GEMM1 half: S[nloc][1024] = nd ; 2-phase dbuf, 8 K-steps ----------------
__global__ __launch_bounds__(256) void k_gemm1t(const ushort* __restrict__ XS3h,
                                                const ushort* __restrict__ WB,
                                                const float* __restrict__ wsq,
                                                const float* __restrict__ xsqh,
                                                float* __restrict__ S) {
  __shared__ __align__(16) ushort Asl[2][8192];
  __shared__ __align__(16) ushort Bsl[2][8192];
  __shared__ float xsl[128];
  __shared__ float wsl[128];
  int t = threadIdx.x;
  int h = blockIdx.x;                 // 0..1023
  int xcd = h & 7, seq = h >> 3;      // round-robin XCD assumption (perf-only)
  int kt = seq & 7;
  int nt = xcd * 16 + (seq >> 3);
  int n0 = nt * 128;
  int k0 = kt * 128;
  int l = t & 63, wid = t >> 6;
  int wr = wid >> 1, wc = wid & 1;
  int hi = l >> 4, c = l & 15;

  if (t < 128) { xsl[t] = xsqh[n0 + t]; wsl[t] = wsq[k0 + t]; }

  f32x4 zero = {0.f, 0.f, 0.f, 0.f};
  f32x4 acc[4][4];
#pragma unroll
  for (int i = 0; i < 4; ++i)
#pragma unroll
    for (int j = 0; j < 4; ++j) acc[i][j] = zero;

  const char* XSb = (const char*)XS3h;
  const char* WBb = (const char*)WB;
  int lr = l >> 3;
  int lsw = ((l & 7) ^ lr) << 4;

#define STAGE(s_, b_)                                                              \
  {                                                                                \
    size_t bofs_ = (size_t)((s_) & 3) << 7;                                        \
    size_t aofs_ = ((s_) < 4) ? ((size_t)(s_) << 7)                                \
                              : (size_t)(512 + (((s_) - 4) << 7));                 \
    char* Ad_ = (char*)Asl + (b_) * 16384;                                         \
    char* Bd_ = (char*)Bsl + (b_) * 16384;                                         \
    _Pragma("unroll")                                                              \
    for (int q_ = 0; q_ < 4; ++q_) {                                               \
      int seg_ = wid * 32 + q_ * 8;                                                \
      GLOAD_LDS16(XSb + (size_t)(n0 + seg_ + lr) * 1536 + aofs_ + lsw,             \
                  Ad_ + seg_ * 128);                                               \
      GLOAD_LDS16(WBb + (size_t)(k0 + seg_ + lr) * 512 + bofs_ + lsw,              \
                  Bd_ + seg_ * 128);                                               \
    }                                                                              \
  }

  STAGE(0, 0);
  asm volatile("s_waitcnt vmcnt(0)" ::: "memory");
  __builtin_amdgcn_s_barrier();
  __builtin_amdgcn_sched_barrier(0);

  int buf = 0;
  for (int s = 0; s < 8; ++s) {
    if (s < 7) STAGE(s + 1, buf ^ 1);
    const ushort* Ab = &Asl[buf][0];
    const ushort* Bb = &Bsl[buf][0];
#pragma unroll
    for (int kk = 0; kk < 2; ++kk) {
      bf16x8 af[4], bg[4];
#pragma unroll
      for (int i = 0; i < 4; ++i) {
        int row = wr * 64 + i * 16 + c;
        int ch = (kk * 4 + hi) ^ (row & 7);
        af[i] = *(const bf16x8*)&Ab[row * 64 + ch * 8];
      }
#pragma unroll
      for (int j = 0; j < 4; ++j) {
        int row = wc * 64 + j * 16 + c;
        int ch = (kk * 4 + hi) ^ (row & 7);
        bg[j] = *(const bf16x8*)&Bb[row * 64 + ch * 8];
      }
#pragma unroll
      for (int i = 0; i < 4; ++i)
#pragma unroll
        for (int j = 0; j < 4; ++j)
          acc[i][j] = __builtin_amdgcn_mfma_f32_16x16x32_bf16(af[i], bg[j], acc[i][j], 0, 0, 0);
    }
    asm volatile("s_waitcnt vmcnt(0)" ::: "memory");
    __builtin_amdgcn_s_barrier();
    buf ^= 1;
  }
#undef STAGE

  // epilogue: nd + S store
#pragma unroll
  for (int i = 0; i < 4; ++i) {
#pragma unroll
    for (int r = 0; r < 4; ++r) {
      int nl = wr * 64 + i * 16 + hi * 4 + r;
      float xs = xsl[nl];
#pragma unroll
      for (int j = 0; j < 4; ++j) {
        int kl = wc * 64 + j * 16 + c;
        float nd = fmaf(2.f, acc[i][j][r], -(xs + wsl[kl]));
        S[(size_t)(n0 + nl) * 1024 + k0 + kl] = nd;
      }
    }
  }
}

// ---------------- fused rowstat+rowwrite (half 0 only): stats + softT panel ----------------
// 512 thr = 8 waves; phase 1: wave handles 8 rows (stats, top2, entropy; M/inv -> LDS);
// phase 2: rowwrite's verified transpose loop (S re-read is L2-warm).
__global__ __launch_bounds__(512) void k_rowfuse(const float* __restrict__ S,
                                                 const float* __restrict__ Gh,
                                                 float* __restrict__ benth,
                                                 int* __restrict__ t2igh,
                                                 ushort* __restrict__ sTp) {
  __shared__ ushort lds[64 * 65];
  __shared__ float Ml[64], Il[64];
  __shared__ float went[8];
  int t = threadIdx.x;
  int l = t & 63, wv = t >> 6;
  int n0 = blockIdx.x * 64;
  float entacc = 0.f;
  for (int it = 0; it < 8; ++it) {
    int nloc = wv * 8 + it;
    int n = n0 + nloc;
    const float* row = S + ((size_t)n << 10);
    const float* grow = Gh + ((size_t)n << 10);
    float v[16];
    float mx = -3.0e38f;
    float v1 = -3.0e38f, v2 = -3.0e38f;
    int i1 = 0x7fffffff, i2 = 0x7fffffff;
#pragma unroll
    for (int j = 0; j < 4; ++j) {
      float4 a = *(const float4*)&row[j * 256 + l * 4];
      float4 gg = *(const float4*)&grow[j * 256 + l * 4];
      float av[4] = {a.x, a.y, a.z, a.w};
      float gv[4] = {gg.x, gg.y, gg.z, gg.w};
#pragma unroll
      for (int q = 0; q < 4; ++q) {
        v[j * 4 + q] = av[q];
        mx = fmaxf(mx, av[q]);
        float sc = av[q] + gv[q];
        int kk = j * 256 + l * 4 + q;
        if (sc > v1 || (sc == v1 && kk < i1)) { v2 = v1; i2 = i1; v1 = sc; i1 = kk; }
        else if (sc > v2 || (sc == v2 && kk < i2)) { v2 = sc; i2 = kk; }
      }
    }
#pragma unroll
    for (int off = 1; off < 64; off <<= 1) {
      mx = fmaxf(mx, __shfl_xor(mx, off));
      float ov1 = __shfl_xor(v1, off), ov2 = __shfl_xor(v2, off);
      int oi1 = __shfl_xor(i1, off), oi2 = __shfl_xor(i2, off);
      bool fB = (ov1 > v1) || (ov1 == v1 && oi1 < i1);
      float nv1 = fB ? ov1 : v1; int ni1 = fB ? oi1 : i1;
      float ca = fB ? v1 : ov1;  int cia = fB ? i1 : oi1;
      float cb = fB ? ov2 : v2;  int cib = fB ? oi2 : i2;
      bool sB = (cb > ca) || (cb == ca && cib < cia);
      v1 = nv1; i1 = ni1;
      v2 = sB ? cb : ca; i2 = sB ? cib : cia;
    }
    float M = 2.f * mx;
    float e[16]; float ps = 0.f;
#pragma unroll
    for (int u = 0; u < 16; ++u) { e[u] = __expf(fmaf(2.f, v[u], -M)); ps += e[u]; }
    ps = wred_sum(ps);
    float inv = 1.f / ps;
    float ent = 0.f;
#pragma unroll
    for (int u = 0; u < 16; ++u) {
      float sfv = e[u] * inv;
      ent += sfv * __logf(fmaxf(sfv, 1e-8f));
    }
    ent = wred_sum(ent);
    entacc += ent;
    if (l == 0) {
      t2igh[n * 2] = i1; t2igh[n * 2 + 1] = i2;
      Ml[nloc] = M; Il[nloc] = inv;
    }
  }
  if (l == 0) went[wv] = entacc;
  __syncthreads();
  if (t == 0) {
    float s = 0.f;
#pragma unroll
    for (int q = 0; q < 8; ++q) s += went[q];
    benth[blockIdx.x] = s;
  }
  // phase 2: soft recompute + transpose write (rowwrite verbatim)
  int row2 = t >> 3, c8 = (t & 7) * 8;
  float M2 = Ml[row2], inv2 = Il[row2];
  for (int kt = 0; kt < 16; ++kt) {
    int k0 = kt * 64;
    const float* sp = &S[(size_t)(n0 + row2) * 1024 + k0 + c8];
    float4 a = *(const float4*)sp;
    float4 b = *(const float4*)(sp + 4);
    float sv[8] = {a.x, a.y, a.z, a.w, b.x, b.y, b.z, b.w};
    ushort* d = &lds[row2 * 65 + c8];
#pragma unroll
    for (int j = 0; j < 8; ++j)
      d[j] = f2bf(__expf(fmaf(2.f, sv[j], -M2)) * inv2);
    __syncthreads();
    int krow = t >> 3, nc8 = (t & 7) * 8;
    uint* dst = (uint*)&sTp[(size_t)(k0 + krow) * NHALF + n0 + nc8];
#pragma unroll
    for (int j = 0; j < 4; ++j) {
      uint lo = lds[(nc8 + 2 * j) * 65 + krow];
      uint hh = lds[(nc8 + 2 * j + 1) * 65 + krow];
      dst[j] = lo | (hh << 16);
    }
    __syncthreads();
  }
}

// ---------------- row stats (half 1): max, 1/sum, top2, entropy ----------------
__global__ __launch_bounds__(256) void k_rowstat(const float* __restrict__ S,
                                                 const float* __restrict__ Gh,
                                                 float* __restrict__ Mrowh,
                                                 float* __restrict__ Irowh,
                                                 float* __restrict__ benth,
                                                 int* __restrict__ t2igh) {
  __shared__ float went[4];
  int t = threadIdx.x;
  int l = t & 63, wv = t >> 6;
  int n = blockIdx.x * 4 + wv;
  const float* row = S + ((size_t)n << 10);
  const float* grow = Gh + ((size_t)n << 10);
  float v[16];
  float mx = -3.0e38f;
  float v1 = -3.0e38f, v2 = -3.0e38f;
  int i1 = 0x7fffffff, i2 = 0x7fffffff;
#pragma unroll
  for (int j = 0; j < 4; ++j) {
    float4 a = *(const float4*)&row[j * 256 + l * 4];
    float4 gg = *(const float4*)&grow[j * 256 + l * 4];
    float av[4] = {a.x, a.y, a.z, a.w};
    float gv[4] = {gg.x, gg.y, gg.z, gg.w};
#pragma unroll
    for (int q = 0; q < 4; ++q) {
      v[j * 4 + q] = av[q];
      mx = fmaxf(mx, av[q]);
      float sc = av[q] + gv[q];
      int kk = j * 256 + l * 4 + q;
      if (sc > v1 || (sc == v1 && kk < i1)) { v2 = v1; i2 = i1; v1 = sc; i1 = kk; }
      else if (sc > v2 || (sc == v2 && kk < i2)) { v2 = sc; i2 = kk; }
    }
  }
#pragma unroll
  for (int off = 1; off < 64; off <<= 1) {
    mx = fmaxf(mx, __shfl_xor(mx, off));
    float ov1 = __shfl_xor(v1, off), ov2 = __shfl_xor(v2, off);
    int oi1 = __shfl_xor(i1, off), oi2 = __shfl_xor(i2, off);
    bool fB = (ov1 > v1) || (ov1 == v1 && oi1 < i1);
    float nv1 = fB ? ov1 : v1; int ni1 = fB ? oi1 : i1;
    float ca = fB ? v1 : ov1;  int cia = fB ? i1 : oi1;
    float cb = fB ? ov2 : v2;  int cib = fB ? oi2 : i2;
    bool sB = (cb > ca) || (cb == ca && cib < cia);
    v1 = nv1; i1 = ni1;
    v2 = sB ? cb : ca; i2 = sB ? cib : cia;
  }
  float M = 2.f * mx;
  float e[16]; float ps = 0.f;
#pragma unroll
  for (int u = 0; u < 16; ++u) { e[u] = __expf(fmaf(2.f, v[u], -M)); ps += e[u]; }
  ps = wred_sum(ps);
  float inv = 1.f / ps;
  float ent = 0.f;
#pragma unroll
  for (int u = 0; u < 16; ++u) {
    float sfv = e[u] * inv;
    ent += sfv * __logf(fmaxf(sfv, 1e-8f));
  }
  ent = wred_sum(ent);
  if (l == 0) {
    t2igh[n * 2] = i1; t2igh[n * 2 + 1] = i2;
    Mrowh[n] = M; Irowh[n] = inv;
    went[wv] = ent;
  }
  __syncthreads();
  if (t == 0) benth[blockIdx.x] = went[0] + went[1] + went[2] + went[3];
}

// ---------------- soft recompute + bf16 transpose write (half 1) ----------------
__global__ __launch_bounds__(512) void k_rowwrite(const float* __restrict__ S,
                                                  const float* __restrict__ Mrowh,
                                                  const float* __restrict__ Irowh,
                                                  ushort* __restrict__ sTp) {
  __shared__ ushort lds[64 * 65];
  __shared__ float Ml[64], Il[64];
  int t = threadIdx.x;
  int n0 = blockIdx.x * 64;
  if (t < 64) { Ml[t] = Mrowh[n0 + t]; Il[t] = Irowh[n0 + t]; }
  __syncthreads();
  for (int kt = 0; kt < 16; ++kt) {
    int k0 = kt * 64;
    int row = t >> 3, c8 = (t & 7) * 8;
    float M = Ml[row], inv = Il[row];
    const float* sp = &S[(size_t)(n0 + row) * 1024 + k0 + c8];
    float4 a = *(const float4*)sp;
    float4 b = *(const float4*)(sp + 4);
    float sv[8] = {a.x, a.y, a.z, a.w, b.x, b.y, b.z, b.w};
    ushort* d = &lds[row * 65 + c8];
#pragma unroll
    for (int j = 0; j < 8; ++j)
      d[j] = f2bf(__expf(fmaf(2.f, sv[j], -M)) * inv);
    __syncthreads();
    int krow = t >> 3, nc8 = (t & 7) * 8;
    uint* dst = (uint*)&sTp[(size_t)(k0 + krow) * NHALF + n0 + nc8];
#pragma unroll
    for (int j = 0; j < 4; ++j) {
      uint lo = lds[(nc8 + 2 * j) * 65 + krow];
      uint hh = lds[(nc8 + 2 * j + 1) * 65 + krow];
      dst[j] = lo | (hh << 16);
    }
    __syncthreads();
  }
}

// ---------------- exact argmax refinement ----------------
__global__ __launch_bounds__(256) void k_refine(const ushort* __restrict__ XS3,
                                                const float* __restrict__ w,
                                                const float* __restrict__ wsq,
                                                const float* __restrict__ xsq,
                                                const float* __restrict__ G,
                                                const int* __restrict__ t2ig,
                                                int* __restrict__ idxArr,
                                                float* __restrict__ hcnt) {
  int t = threadIdx.x;
  int l = t & 63, wv = t >> 6;
  int base = blockIdx.x * 64 + wv * 16;
  int d0 = l * 4;
  for (int rr = 0; rr < 16; ++rr) {
    int n = base + rr;
    const ushort* p = XS3 + (size_t)n * 768;
    union { uint2 q; ushort u[4]; } ha, ma, la;
    ha.q = *(const uint2*)&p[d0];
    ma.q = *(const uint2*)&p[256 + d0];
    la.q = *(const uint2*)&p[512 + d0];
    float xv[4];
#pragma unroll
    for (int q = 0; q < 4; ++q) xv[q] = bf2f(ha.u[q]) + bf2f(ma.u[q]) + bf2f(la.u[q]);
    float xs = xsq[n];
    int ia = t2ig[n * 2], ib = t2ig[n * 2 + 1];
    float sc[2];
    int ids[2] = {ia, ib};
#pragma unroll
    for (int cdd = 0; cdd < 2; ++cdd) {
      int id = ids[cdd];
      const float* wr = w + (size_t)id * DDIM;
      float4 wv4 = *(const float4*)&wr[d0];
      float d = xv[0] * wv4.x + xv[1] * wv4.y + xv[2] * wv4.z + xv[3] * wv4.w;
      d = wred_sum(d);
      sc[cdd] = fmaf(2.f, d, -xs) - wsq[id] + G[((size_t)n << 10) + id];
    }
    int win = (sc[1] > sc[0] || (sc[1] == sc[0] && ib < ia)) ? ib : ia;
    if (l == 0) {
      idxArr[n] = win;
      atomicAdd(&hcnt[win], 1.f);
    }
  }
}

// ---------------- quantized output ----------------
__global__ void k_quant(const float* __restrict__ w, const int* __restrict__ idxArr,
                        float* __restrict__ outQ) {
  int n = blockIdx.x * 256 + threadIdx.x;
  int b = n >> 10, m = n & 1023;
  int id = idxArr[n];
  const float* wr = w + (size_t)id * DDIM;
  float* o = outQ + (size_t)b * DDIM * 1024 + m;
#pragma unroll 4
  for (int d = 0; d < DDIM; ++d) o[(size_t)d * 1024] = wr[d];
}

// ---------------- GEMM2 (MFMA bf16) + fused colsum ; XCD-chunked swizzle ----------------
__global__ __launch_bounds__(512) void k_gemm2_mfma(const ushort* __restrict__ sT0,
                                                    const ushort* __restrict__ sT1,
                                                    const float* __restrict__ x,
                                                    float* __restrict__ P,
                                                    float* __restrict__ colsum) {
  __shared__ __align__(16) ushort Abuf[256 * 72];
  __shared__ __align__(16) ushort Bbuf[128 * 72];
  int t = threadIdx.x;
  int h = blockIdx.x;                 // 0..255
  int xcd = h & 7, seq = h >> 3;      // 32 per XCD
  int ns = xcd * 4 + (seq >> 3);
  int ktdt = seq & 7;
  int kt = ktdt & 3, dt = ktdt >> 2;
  int k0 = kt * 256, d0 = dt * 128;
  int l = t & 63, wv = t >> 6;
  int wk = wv >> 1, wd = wv & 1;
  const ushort* Abase = (ns < 16) ? sT0 : sT1;
  size_t nloc0 = (size_t)(ns & 15) * 1024;
  f32x4 zero = {0.f, 0.f, 0.f, 0.f};
  f32x4 acc[4][4];
#pragma unroll
  for (int i = 0; i < 4; ++i)
#pragma unroll
    for (int j = 0; j < 4; ++j) acc[i][j] = zero;
  float colacc[4] = {0.f, 0.f, 0.f, 0.f};

  int colv = (t & 7) * 8;
  int rbase = t >> 3;
  for (int s = 0; s < 16; ++s) {
#pragma unroll
    for (int p = 0; p < 4; ++p) {
      int row = p * 64 + rbase;
      const uint* ap = (const uint*)(Abase + (size_t)(k0 + row) * NHALF + nloc0 + s * 64 + colv);
      uint4 v; v.x = ap[0]; v.y = ap[1]; v.z = ap[2]; v.w = ap[3];
      *(uint4*)&Abuf[row * 72 + colv] = v;
    }
#pragma unroll
    for (int p = 0; p < 2; ++p) {
      int row = p * 64 + rbase;
      const float* xp = &x[((size_t)ns * DDIM + d0 + row) * 1024 + s * 64 + colv];
      float4 a = *(const float4*)xp;
      float4 b = *(const float4*)(xp + 4);
      union { ushort u[8]; uint4 q; } pk;
      pk.u[0] = f2bf(a.x); pk.u[1] = f2bf(a.y); pk.u[2] = f2bf(a.z); pk.u[3] = f2bf(a.w);
      pk.u[4] = f2bf(b.x); pk.u[5] = f2bf(b.y); pk.u[6] = f2bf(b.z); pk.u[7] = f2bf(b.w);
      *(uint4*)&Bbuf[row * 72 + colv] = pk.q;
    }
    __syncthreads();
    bf16x8 af[4], bfr[4];
#pragma unroll
    for (int nb2 = 0; nb2 < 2; ++nb2) {
#pragma unroll
      for (int sub = 0; sub < 4; ++sub) {
        af[sub] = *(const bf16x8*)&Abuf[(wk * 64 + sub * 16 + (l & 15)) * 72 + nb2 * 32 + (l >> 4) * 8];
        bfr[sub] = *(const bf16x8*)&Bbuf[(wd * 64 + sub * 16 + (l & 15)) * 72 + nb2 * 32 + (l >> 4) * 8];
      }
      if (dt == 0 && wd == 0) {
#pragma unroll
        for (int sub = 0; sub < 4; ++sub)
#pragma unroll
          for (int q = 0; q < 8; ++q)
            colacc[sub] += bf2f((ushort)af[sub][q]);
      }
#pragma unroll
      for (int i = 0; i < 4; ++i)
#pragma unroll
        for (int j = 0; j < 4; ++j)
          acc[i][j] = __builtin_amdgcn_mfma_f32_16x16x32_bf16(af[i], bfr[j], acc[i][j], 0, 0, 0);
    }
    __syncthreads();
  }
  float* Pb = P + (size_t)ns * (KCB * DDIM);
#pragma unroll
  for (int i = 0; i < 4; ++i)
#pragma unroll
    for (int j = 0; j < 4; ++j) {
#pragma unroll
      for (int r = 0; r < 4; ++r) {
        int k = k0 + wk * 64 + i * 16 + (l >> 4) * 4 + r;
        int d = d0 + wd * 64 + j * 16 + (l & 15);
        Pb[(size_t)k * DDIM + d] = acc[i][j][r];
      }
    }
  if (dt == 0 && wd == 0) {
#pragma unroll
    for (int sub = 0; sub < 4; ++sub) {
      float s = colacc[sub];
      s += __shfl_xor(s, 16);
      s += __shfl_xor(s, 32);
      if (l < 16) atomicAdd(&colsum[k0 + wk * 64 + sub * 16 + l], s);
    }
  }
}

// ---------------- finalize scalars, new_count ----------------
__global__ void k_final1(const float* __restrict__ ema_count, const float* __restrict__ colsum,
                         const float* __restrict__ hcnt, const float* __restrict__ bent,
                         float* __restrict__ ncnt, float* __restrict__ out) {
  __shared__ float red[1024];
  int t = threadIdx.x;
  const float onem = 1.0f - 0.99f;
  float nc = ema_count[t] * 0.99f + colsum[t] * onem;
  nc = (nc + 1e-5f) / (32768.0f + 1024.0f * 1e-5f) * 32768.0f;
  out[O_NCNT + t] = nc;
  ncnt[t] = nc;
  float s = 0.f;
  for (int i = t; i < 4352; i += 1024) s += bent[i];
  red[t] = s;
  __syncthreads();
  for (int off = 512; off > 0; off >>= 1) { if (t < off) red[t] += red[t + off]; __syncthreads(); }
  if (t == 0) out[O_LOSS] = 0.25f * (red[0] / 32768.0f);
  __syncthreads();
  float avg = hcnt[t] * (1.0f / 32768.0f);
  red[t] = avg * logf(avg + 1e-10f);
  __syncthreads();
  for (int off = 512; off > 0; off >>= 1) { if (t < off) red[t] += red[t + off]; __syncthreads(); }
  if (t == 0) out[O_PERP] = expf(-red[0]);
}

// ---------------- reduce dw partials + new_ema_weight & new_embedding ----------------
__global__ void k_reduce_final2(const float* __restrict__ P, const float* __restrict__ ema_w,
                                const float* __restrict__ ncnt, float* __restrict__ outEW,
                                float* __restrict__ outEMB) {
  int i = blockIdx.x * 256 + threadIdx.x;
  float s = 0.f;
#pragma unroll
  for (int ns = 0; ns < 32; ++ns) s += P[(size_t)ns * (KCB * DDIM) + i];
  float ew = ema_w[i] * 0.99f + s * 0.01f;
  outEW[i] = ew;
  outEMB[i] = ew / ncnt[i >> 8];
}

// ---------------- one-hot encodings (overwrites E scratch, last) ----------------
__global__ void k_onehot(const int* __restrict__ idxArr, float* __restrict__ E) {
  int gid = blockIdx.x * 256 + threadIdx.x;
  int n = gid >> 8;
  int k4 = (gid & 255) * 4;
  int id = idxArr[n];
  float2* E2 = (float2*)E;
  size_t base = ((size_t)n * KCB + k4) >> 1;
  float2 vA = {(float)(k4 == id), (float)(k4 + 1 == id)};
  float2 vB = {(float)(k4 + 2 == id), (float)(k4 + 3 == id)};
  E2[base] = vA;
  E2[base + 1] = vB;
}

extern "C" void kernel_launch(void* const* d_in, const int* in_sizes, int n_in,
                              void* d_out, int out_size, void* d_ws, size_t ws_size,
                              hipStream_t stream) {
  const float* x = (const float*)d_in[0];
  const float* w = (const float*)d_in[1];
  const float* ema_count = (const float*)d_in[2];
  const float* ema_w = (const float*)d_in[3];
  const float* g = (const float*)d_in[4];
  float* out = (float*)d_out;
  float* ws = (float*)d_ws;

  float* wsq    = ws + W_WSQ;
  float* xsq    = ws + W_XSQ;
  int*   idxArr = (int*)(ws + W_IDX);
  float* colsum = ws + W_COL;
  float* hcnt   = ws + W_HCNT;
  float* bent   = ws + W_BENT;
  float* ncnt   = ws + W_NCNT;
  int*   top2i  = (int*)(ws + W_T2I);
  ushort* WB    = (ushort*)(ws + W_WB);
  float* Mrow   = ws + W_MROW;
  float* Irow   = ws + W_IROW;

  float* outQ = out + O_Q;
  float* outE = out + O_ENC;

  ushort* XS3    = (ushort*)(outE + E_XS3);     // 16B-aligned
  float*  Sslot  = outE + E_S;                  // 16B-aligned
  ushort* softT1 = (ushort*)(outE + E_XS3);     // overwrites XS3 after refine
  ushort* softT0 = (ushort*)outQ;               // Q region (4B-aligned: uint ops only)

  k_init<<<4, 256, 0, stream>>>(hcnt, colsum);
  k_wsplit<<<256, 256, 0, stream>>>(w, wsq, WB);
  k_xsplit<<<1024, 256, 0, stream>>>(x, XS3, xsq);
  // ---- half 0 (rows 0..16383): fused stats + softT0 ----
  k_gemm1t<<<1024, 256, 0, stream>>>(XS3, WB, wsq, xsq, Sslot);
  k_rowfuse<<<256, 512, 0, stream>>>(Sslot, g, bent, top2i, softT0);
  // ---- half 1 (rows 16384..32767): split path (refine needs XS3 before softT1) ----
  k_gemm1t<<<1024, 256, 0, stream>>>(XS3 + (size_t)NHALF * 768, WB,
                                     wsq, xsq + NHALF, Sslot);
  k_rowstat<<<4096, 256, 0, stream>>>(Sslot, g + (size_t)NHALF * 1024,
                                      Mrow, Irow, bent + 256, top2i + NHALF * 2);
  k_refine<<<512, 256, 0, stream>>>(XS3, w, wsq, xsq, g, top2i, idxArr, hcnt);
  k_rowwrite<<<256, 512, 0, stream>>>(Sslot, Mrow, Irow, softT1);  // over XS3
  k_gemm2_mfma<<<256, 512, 0, stream>>>(softT0, softT1, x, Sslot, colsum);  // P -> Sslot head
  k_final1<<<1, 1024, 0, stream>>>(ema_count, colsum, hcnt, bent, ncnt, out);
  k_reduce_final2<<<1024, 256, 0, stream>>>(Sslot, ema_w, ncnt, out + O_EMAW, out + O_EMB);
  k_quant<<<128, 256, 0, stream>>>(w, idxArr, outQ);       // overwrites softT0
  k_onehot<<<32768, 256, 0, stream>>>(idxArr, outE);       // overwrites all E scratch
}

// Round 14
// 324.405 us; speedup vs baseline: 1.0282x; 1.0282x over previous
//
#include <hip/hip_runtime.h>
#include <math.h>

// Problem constants
#define NROWS 32768   // B*H*W
#define KCB   1024
#define DDIM  256
#define NHALF 16384

// Output offsets (floats)
#define O_LOSS 0
#define O_Q    1
#define O_PERP 8388609
#define O_ENC  8388610
#define O_NCNT 41943042
#define O_EMAW 41944066
#define O_EMB  42206210

// E-region scratch (floats rel. outE; region = 33,554,432 floats):
//   XS3   @ 2          : bf16 [32768][768] (hi|mid|lo) = 12,582,912 floats (16B-aligned)
//   Sslot @ 12582914   : fp32 [16384][1024] nd values -> ends 29,360,130
//   softT1 aliases XS3 base (written after refine); P (bf16, 16.8 MB) aliases Sslot head.
#define E_XS3   2
#define E_S     12582914

// Workspace offsets (floats)
#define W_WSQ  0        // 1024
#define W_XSQ  1024     // 32768
#define W_IDX  33792    // 32768 (int)
#define W_COL  66560    // 1024
#define W_HCNT 67584    // 1024
#define W_BENT 68608    // 8192 (h0: 256, h1: 4096 -> 4352 used)
#define W_T2I  77824    // 65536 (int)
#define W_WB   143360   // 1024*256 ushorts = 131072 floats (w_hi only)
#define W_MROW 274432   // 16384 (h1 only)
#define W_IROW 307200   // 16384 (h1 only)

typedef __attribute__((ext_vector_type(8))) short bf16x8;
typedef __attribute__((ext_vector_type(4))) float f32x4;

#define GLOAD_LDS16(g, l) __builtin_amdgcn_global_load_lds( \
    (const __attribute__((address_space(1))) unsigned int*)(g), \
    (__attribute__((address_space(3))) unsigned int*)(l), 16, 0, 0)

__device__ __forceinline__ float wred_sum(float v) {
#pragma unroll
  for (int off = 32; off > 0; off >>= 1) v += __shfl_xor(v, off);
  return v;
}
__device__ __forceinline__ ushort f2bf(float f) {
  union { float f; unsigned u; } c; c.f = f;
  unsigned u = c.u;
  return (ushort)((u + 0x7fffu + ((u >> 16) & 1u)) >> 16);  // RNE
}
__device__ __forceinline__ float bf2f(ushort h) {
  union { unsigned u; float f; } c; c.u = ((unsigned)h) << 16;
  return c.f;
}

// ---------------- init ----------------
__global__ void k_init(float* __restrict__ hcnt, float* __restrict__ colsum) {
  int i = blockIdx.x * 256 + threadIdx.x;
  if (i < 1024) { hcnt[i] = 0.f; colsum[i] = 0.f; }
}

// ---------------- w -> wsq + WB [k][256] = w_hi ----------------
__global__ void k_wsplit(const float* __restrict__ w, float* __restrict__ wsq,
                         ushort* __restrict__ WB) {
  int t = threadIdx.x;
  int lane = t & 63, wv = t >> 6;
  int k = blockIdx.x * 4 + wv;
  int d0 = lane * 4;
  float4 v = *(const float4*)&w[(size_t)k * DDIM + d0];
  float s = v.x * v.x + v.y * v.y + v.z * v.z + v.w * v.w;
  s = wred_sum(s);
  if (lane == 0) wsq[k] = s;
  float vv[4] = {v.x, v.y, v.z, v.w};
  union { ushort u[4]; uint2 q; } hh;
#pragma unroll
  for (int q = 0; q < 4; ++q) hh.u[q] = f2bf(vv[q]);
  *(uint2*)&WB[(size_t)k * 256 + d0] = hh.q;
}

// ---------------- x -> XS3 (3-way bf16 split) + xsq ----------------
__global__ __launch_bounds__(256) void k_xsplit(const float* __restrict__ x,
                                                ushort* __restrict__ XS3,
                                                float* __restrict__ xsq) {
  __shared__ __align__(16) ushort sl[32 * 776];
  __shared__ float sq[32 * 9];
  int t = threadIdx.x;
  int b = blockIdx.x >> 5, mt = blockIdx.x & 31;
  int m0 = mt * 32, mloc = t & 31, dgrp = t >> 5;
  const float* xb = x + (size_t)b * DDIM * 1024 + m0 + mloc;
  float s = 0.f;
#pragma unroll
  for (int jj = 0; jj < 8; ++jj) {
    int d0 = dgrp * 32 + jj * 4;
    float vv[4];
#pragma unroll
    for (int q = 0; q < 4; ++q) vv[q] = xb[(size_t)(d0 + q) * 1024];
    union { ushort u[4]; uint2 q; } hh, mi, lo;
#pragma unroll
    for (int q = 0; q < 4; ++q) {
      float v = vv[q];
      ushort h = f2bf(v);
      float r1 = v - bf2f(h);
      ushort m_ = f2bf(r1);
      float r2 = r1 - bf2f(m_);
      hh.u[q] = h; mi.u[q] = m_; lo.u[q] = f2bf(r2);
      s = fmaf(v, v, s);
    }
    int base = mloc * 776;
    *(uint2*)&sl[base + d0] = hh.q;
    *(uint2*)&sl[base + 256 + d0] = mi.q;
    *(uint2*)&sl[base + 512 + d0] = lo.q;
  }
  sq[mloc * 9 + dgrp] = s;
  __syncthreads();
  if (t < 32) {
    float ss = 0.f;
#pragma unroll
    for (int gq = 0; gq < 8; ++gq) ss += sq[t * 9 + gq];
    xsq[b * 1024 + m0 + t] = ss;
  }
  ushort* dst = XS3 + (size_t)(b * 1024 + m0) * 768;
#pragma unroll
  for (int p = 0; p < 12; ++p) {
    int idx = p * 256 + t;
    int row = idx / 96;
    int co = idx - row * 96;
    *(uint4*)&dst[(size_t)row * 768 + co * 8] = *(uint4*)&sl[row * 776 + co * 8];
  }
}

// ---------------- GEMM1 half: S[nloc][1024] = nd ; 2-phase dbuf, 8 K-steps ----------------
__global__ __launch_bounds__(256) void k_gemm1t(const ushort* __restrict__ XS3h,
                                                const ushort* __restrict__ WB,
                                                const float* __restrict__ wsq,
                                                const float* __restrict__ xsqh,
                                                float* __restrict__ S) {
  __shared__ __align__(16) ushort Asl[2][8192];
  __shared__ __align__(16) ushort Bsl[2][8192];
  __shared__ float xsl[128];
  __shared__ float wsl[128];
  int t = threadIdx.x;
  int h = blockIdx.x;                 // 0..1023
  int xcd = h & 7, seq = h >> 3;      // round-robin XCD assumption (perf-only)
  int kt = seq & 7;
  int nt = xcd * 16 + (seq >> 3);
  int n0 = nt * 128;
  int k0 = kt * 128;
  int l = t & 63, wid = t >> 6;
  int wr = wid >> 1, wc = wid & 1;
  int hi = l >> 4, c = l & 15;

  if (t < 128) { xsl[t] = xsqh[n0 + t]; wsl[t] = wsq[k0 + t]; }

  f32x4 zero = {0.f, 0.f, 0.f, 0.f};
  f32x4 acc[4][4];
#pragma unroll
  for (int i = 0; i < 4; ++i)
#pragma unroll
    for (int j = 0; j < 4; ++j) acc[i][j] = zero;

  const char* XSb = (const char*)XS3h;
  const char* WBb = (const char*)WB;
  int lr = l >> 3;
  int lsw = ((l & 7) ^ lr) << 4;

#define STAGE(s_, b_)                                                              \
  {                                                                                \
    size_t bofs_ = (size_t)((s_) & 3) << 7;                                        \
    size_t aofs_ = ((s_) < 4) ? ((size_t)(s_) << 7)                                \
                              : (size_t)(512 + (((s_) - 4) << 7));                 \
    char* Ad_ = (char*)Asl + (b_) * 16384;                                         \
    char* Bd_ = (char*)Bsl + (b_) * 16384;                                         \
    _Pragma("unroll")                                                              \
    for (int q_ = 0; q_ < 4; ++q_) {                                               \
      int seg_ = wid * 32 + q_ * 8;                                                \
      GLOAD_LDS16(XSb + (size_t)(n0 + seg_ + lr) * 1536 + aofs_ + lsw,             \
                  Ad_ + seg_ * 128);                                               \
      GLOAD_LDS16(WBb + (size_t)(k0 + seg_ + lr) * 512 + bofs_ + lsw,              \
                  Bd_ + seg_ * 128);                                               \
    }                                                                              \
  }

  STAGE(0, 0);
  asm volatile("s_waitcnt vmcnt(0)" ::: "memory");
  __builtin_amdgcn_s_barrier();
  __builtin_amdgcn_sched_barrier(0);

  int buf = 0;
  for (int s = 0; s < 8; ++s) {
    if (s < 7) STAGE(s + 1, buf ^ 1);
    const ushort* Ab = &Asl[buf][0];
    const ushort* Bb = &Bsl[buf][0];
#pragma unroll
    for (int kk = 0; kk < 2; ++kk) {
      bf16x8 af[4], bg[4];
#pragma unroll
      for (int i = 0; i < 4; ++i) {
        int row = wr * 64 + i * 16 + c;
        int ch = (kk * 4 + hi) ^ (row & 7);
        af[i] = *(const bf16x8*)&Ab[row * 64 + ch * 8];
      }
#pragma unroll
      for (int j = 0; j < 4; ++j) {
        int row = wc * 64 + j * 16 + c;
        int ch = (kk * 4 + hi) ^ (row & 7);
        bg[j] = *(const bf16x8*)&Bb[row * 64 + ch * 8];
      }
#pragma unroll
      for (int i = 0; i < 4; ++i)
#pragma unroll
        for (int j = 0; j < 4; ++j)
          acc[i][j] = __builtin_amdgcn_mfma_f32_16x16x32_bf16(af[i], bg[j], acc[i][j], 0, 0, 0);
    }
    asm volatile("s_waitcnt vmcnt(0)" ::: "memory");
    __builtin_amdgcn_s_barrier();
    buf ^= 1;
  }
#undef STAGE

  // epilogue: nd + S store
#pragma unroll
  for (int i = 0; i < 4; ++i) {
#pragma unroll
    for (int r = 0; r < 4; ++r) {
      int nl = wr * 64 + i * 16 + hi * 4 + r;
      float xs = xsl[nl];
#pragma unroll
      for (int j = 0; j < 4; ++j) {
        int kl = wc * 64 + j * 16 + c;
        float nd = fmaf(2.f, acc[i][j][r], -(xs + wsl[kl]));
        S[(size_t)(n0 + nl) * 1024 + k0 + kl] = nd;
      }
    }
  }
}

// ---------------- fused rowstat+rowwrite (half 0): stats + softT panel ----------------
__global__ __launch_bounds__(512) void k_rowfuse(const float* __restrict__ S,
                                                 const float* __restrict__ Gh,
                                                 float* __restrict__ benth,
                                                 int* __restrict__ t2igh,
                                                 ushort* __restrict__ sTp) {
  __shared__ ushort lds[64 * 65];
  __shared__ float Ml[64], Il[64];
  __shared__ float went[8];
  int t = threadIdx.x;
  int l = t & 63, wv = t >> 6;
  int n0 = blockIdx.x * 64;
  float entacc = 0.f;
  for (int it = 0; it < 8; ++it) {
    int nloc = wv * 8 + it;
    int n = n0 + nloc;
    const float* row = S + ((size_t)n << 10);
    const float* grow = Gh + ((size_t)n << 10);
    float v[16];
    float mx = -3.0e38f;
    float v1 = -3.0e38f, v2 = -3.0e38f;
    int i1 = 0x7fffffff, i2 = 0x7fffffff;
#pragma unroll
    for (int j = 0; j < 4; ++j) {
      float4 a = *(const float4*)&row[j * 256 + l * 4];
      float4 gg = *(const float4*)&grow[j * 256 + l * 4];
      float av[4] = {a.x, a.y, a.z, a.w};
      float gv[4] = {gg.x, gg.y, gg.z, gg.w};
#pragma unroll
      for (int q = 0; q < 4; ++q) {
        v[j * 4 + q] = av[q];
        mx = fmaxf(mx, av[q]);
        float sc = av[q] + gv[q];
        int kk = j * 256 + l * 4 + q;
        if (sc > v1 || (sc == v1 && kk < i1)) { v2 = v1; i2 = i1; v1 = sc; i1 = kk; }
        else if (sc > v2 || (sc == v2 && kk < i2)) { v2 = sc; i2 = kk; }
      }
    }
#pragma unroll
    for (int off = 1; off < 64; off <<= 1) {
      mx = fmaxf(mx, __shfl_xor(mx, off));
      float ov1 = __shfl_xor(v1, off), ov2 = __shfl_xor(v2, off);
      int oi1 = __shfl_xor(i1, off), oi2 = __shfl_xor(i2, off);
      bool fB = (ov1 > v1) || (ov1 == v1 && oi1 < i1);
      float nv1 = fB ? ov1 : v1; int ni1 = fB ? oi1 : i1;
      float ca = fB ? v1 : ov1;  int cia = fB ? i1 : oi1;
      float cb = fB ? ov2 : v2;  int cib = fB ? oi2 : i2;
      bool sB = (cb > ca) || (cb == ca && cib < cia);
      v1 = nv1; i1 = ni1;
      v2 = sB ? cb : ca; i2 = sB ? cib : cia;
    }
    float M = 2.f * mx;
    float e[16]; float ps = 0.f;
#pragma unroll
    for (int u = 0; u < 16; ++u) { e[u] = __expf(fmaf(2.f, v[u], -M)); ps += e[u]; }
    ps = wred_sum(ps);
    float inv = 1.f / ps;
    float ent = 0.f;
#pragma unroll
    for (int u = 0; u < 16; ++u) {
      float sfv = e[u] * inv;
      ent += sfv * __logf(fmaxf(sfv, 1e-8f));
    }
    ent = wred_sum(ent);
    entacc += ent;
    if (l == 0) {
      t2igh[n * 2] = i1; t2igh[n * 2 + 1] = i2;
      Ml[nloc] = M; Il[nloc] = inv;
    }
  }
  if (l == 0) went[wv] = entacc;
  __syncthreads();
  if (t == 0) {
    float s = 0.f;
#pragma unroll
    for (int q = 0; q < 8; ++q) s += went[q];
    benth[blockIdx.x] = s;
  }
  // phase 2: soft recompute + transpose write
  int row2 = t >> 3, c8 = (t & 7) * 8;
  float M2 = Ml[row2], inv2 = Il[row2];
  for (int kt = 0; kt < 16; ++kt) {
    int k0 = kt * 64;
    const float* sp = &S[(size_t)(n0 + row2) * 1024 + k0 + c8];
    float4 a = *(const float4*)sp;
    float4 b = *(const float4*)(sp + 4);
    float sv[8] = {a.x, a.y, a.z, a.w, b.x, b.y, b.z, b.w};
    ushort* d = &lds[row2 * 65 + c8];
#pragma unroll
    for (int j = 0; j < 8; ++j)
      d[j] = f2bf(__expf(fmaf(2.f, sv[j], -M2)) * inv2);
    __syncthreads();
    int krow = t >> 3, nc8 = (t & 7) * 8;
    uint* dst = (uint*)&sTp[(size_t)(k0 + krow) * NHALF + n0 + nc8];
#pragma unroll
    for (int j = 0; j < 4; ++j) {
      uint lo = lds[(nc8 + 2 * j) * 65 + krow];
      uint hh = lds[(nc8 + 2 * j + 1) * 65 + krow];
      dst[j] = lo | (hh << 16);
    }
    __syncthreads();
  }
}

// ---------------- row stats (half 1) ----------------
__global__ __launch_bounds__(256) void k_rowstat(const float* __restrict__ S,
                                                 const float* __restrict__ Gh,
                                                 float* __restrict__ Mrowh,
                                                 float* __restrict__ Irowh,
                                                 float* __restrict__ benth,
                                                 int* __restrict__ t2igh) {
  __shared__ float went[4];
  int t = threadIdx.x;
  int l = t & 63, wv = t >> 6;
  int n = blockIdx.x * 4 + wv;
  const float* row = S + ((size_t)n << 10);
  const float* grow = Gh + ((size_t)n << 10);
  float v[16];
  float mx = -3.0e38f;
  float v1 = -3.0e38f, v2 = -3.0e38f;
  int i1 = 0x7fffffff, i2 = 0x7fffffff;
#pragma unroll
  for (int j = 0; j < 4; ++j) {
    float4 a = *(const float4*)&row[j * 256 + l * 4];
    float4 gg = *(const float4*)&grow[j * 256 + l * 4];
    float av[4] = {a.x, a.y, a.z, a.w};
    float gv[4] = {gg.x, gg.y, gg.z, gg.w};
#pragma unroll
    for (int q = 0; q < 4; ++q) {
      v[j * 4 + q] = av[q];
      mx = fmaxf(mx, av[q]);
      float sc = av[q] + gv[q];
      int kk = j * 256 + l * 4 + q;
      if (sc > v1 || (sc == v1 && kk < i1)) { v2 = v1; i2 = i1; v1 = sc; i1 = kk; }
      else if (sc > v2 || (sc == v2 && kk < i2)) { v2 = sc; i2 = kk; }
    }
  }
#pragma unroll
  for (int off = 1; off < 64; off <<= 1) {
    mx = fmaxf(mx, __shfl_xor(mx, off));
    float ov1 = __shfl_xor(v1, off), ov2 = __shfl_xor(v2, off);
    int oi1 = __shfl_xor(i1, off), oi2 = __shfl_xor(i2, off);
    bool fB = (ov1 > v1) || (ov1 == v1 && oi1 < i1);
    float nv1 = fB ? ov1 : v1; int ni1 = fB ? oi1 : i1;
    float ca = fB ? v1 : ov1;  int cia = fB ? i1 : oi1;
    float cb = fB ? ov2 : v2;  int cib = fB ? oi2 : i2;
    bool sB = (cb > ca) || (cb == ca && cib < cia);
    v1 = nv1; i1 = ni1;
    v2 = sB ? cb : ca; i2 = sB ? cib : cia;
  }
  float M = 2.f * mx;
  float e[16]; float ps = 0.f;
#pragma unroll
  for (int u = 0; u < 16; ++u) { e[u] = __expf(fmaf(2.f, v[u], -M)); ps += e[u]; }
  ps = wred_sum(ps);
  float inv = 1.f / ps;
  float ent = 0.f;
#pragma unroll
  for (int u = 0; u < 16; ++u) {
    float sfv = e[u] * inv;
    ent += sfv * __logf(fmaxf(sfv, 1e-8f));
  }
  ent = wred_sum(ent);
  if (l == 0) {
    t2igh[n * 2] = i1; t2igh[n * 2 + 1] = i2;
    Mrowh[n] = M; Irowh[n] = inv;
    went[wv] = ent;
  }
  __syncthreads();
  if (t == 0) benth[blockIdx.x] = went[0] + went[1] + went[2] + went[3];
}

// ---------------- soft recompute + bf16 transpose write (half 1) ----------------
__global__ __launch_bounds__(512) void k_rowwrite(const float* __restrict__ S,
                                                  const float* __restrict__ Mrowh,
                                                  const float* __restrict__ Irowh,
                                                  ushort* __restrict__ sTp) {
  __shared__ ushort lds[64 * 65];
  __shared__ float Ml[64], Il[64];
  int t = threadIdx.x;
  int n0 = blockIdx.x * 64;
  if (t < 64) { Ml[t] = Mrowh[n0 + t]; Il[t] = Irowh[n0 + t]; }
  __syncthreads();
  for (int kt = 0; kt < 16; ++kt) {
    int k0 = kt * 64;
    int row = t >> 3, c8 = (t & 7) * 8;
    float M = Ml[row], inv = Il[row];
    const float* sp = &S[(size_t)(n0 + row) * 1024 + k0 + c8];
    float4 a = *(const float4*)sp;
    float4 b = *(const float4*)(sp + 4);
    float sv[8] = {a.x, a.y, a.z, a.w, b.x, b.y, b.z, b.w};
    ushort* d = &lds[row * 65 + c8];
#pragma unroll
    for (int j = 0; j < 8; ++j)
      d[j] = f2bf(__expf(fmaf(2.f, sv[j], -M)) * inv);
    __syncthreads();
    int krow = t >> 3, nc8 = (t & 7) * 8;
    uint* dst = (uint*)&sTp[(size_t)(k0 + krow) * NHALF + n0 + nc8];
#pragma unroll
    for (int j = 0; j < 4; ++j) {
      uint lo = lds[(nc8 + 2 * j) * 65 + krow];
      uint hh = lds[(nc8 + 2 * j + 1) * 65 + krow];
      dst[j] = lo | (hh << 16);
    }
    __syncthreads();
  }
}

// ---------------- exact argmax refinement ----------------
__global__ __launch_bounds__(256) void k_refine(const ushort* __restrict__ XS3,
                                                const float* __restrict__ w,
                                                const float* __restrict__ wsq,
                                                const float* __restrict__ xsq,
                                                const float* __restrict__ G,
                                                const int* __restrict__ t2ig,
                                                int* __restrict__ idxArr,
                                                float* __restrict__ hcnt) {
  int t = threadIdx.x;
  int l = t & 63, wv = t >> 6;
  int base = blockIdx.x * 64 + wv * 16;
  int d0 = l * 4;
  for (int rr = 0; rr < 16; ++rr) {
    int n = base + rr;
    const ushort* p = XS3 + (size_t)n * 768;
    union { uint2 q; ushort u[4]; } ha, ma, la;
    ha.q = *(const uint2*)&p[d0];
    ma.q = *(const uint2*)&p[256 + d0];
    la.q = *(const uint2*)&p[512 + d0];
    float xv[4];
#pragma unroll
    for (int q = 0; q < 4; ++q) xv[q] = bf2f(ha.u[q]) + bf2f(ma.u[q]) + bf2f(la.u[q]);
    float xs = xsq[n];
    int ia = t2ig[n * 2], ib = t2ig[n * 2 + 1];
    float sc[2];
    int ids[2] = {ia, ib};
#pragma unroll
    for (int cdd = 0; cdd < 2; ++cdd) {
      int id = ids[cdd];
      const float* wr = w + (size_t)id * DDIM;
      float4 wv4 = *(const float4*)&wr[d0];
      float d = xv[0] * wv4.x + xv[1] * wv4.y + xv[2] * wv4.z + xv[3] * wv4.w;
      d = wred_sum(d);
      sc[cdd] = fmaf(2.f, d, -xs) - wsq[id] + G[((size_t)n << 10) + id];
    }
    int win = (sc[1] > sc[0] || (sc[1] == sc[0] && ib < ia)) ? ib : ia;
    if (l == 0) {
      idxArr[n] = win;
      atomicAdd(&hcnt[win], 1.f);
    }
  }
}

// ---------------- quantized output ----------------
__global__ void k_quant(const float* __restrict__ w, const int* __restrict__ idxArr,
                        float* __restrict__ outQ) {
  int n = blockIdx.x * 256 + threadIdx.x;
  int b = n >> 10, m = n & 1023;
  int id = idxArr[n];
  const float* wr = w + (size_t)id * DDIM;
  float* o = outQ + (size_t)b * DDIM * 1024 + m;
#pragma unroll 4
  for (int d = 0; d < DDIM; ++d) o[(size_t)d * 1024] = wr[d];
}

// ---------------- GEMM2 (MFMA bf16) + fused colsum ; P stored bf16 ----------------
__global__ __launch_bounds__(512) void k_gemm2_mfma(const ushort* __restrict__ sT0,
                                                    const ushort* __restrict__ sT1,
                                                    const float* __restrict__ x,
                                                    ushort* __restrict__ P,
                                                    float* __restrict__ colsum) {
  __shared__ __align__(16) ushort Abuf[256 * 72];
  __shared__ __align__(16) ushort Bbuf[128 * 72];
  int t = threadIdx.x;
  int h = blockIdx.x;                 // 0..255
  int xcd = h & 7, seq = h >> 3;      // 32 per XCD
  int ns = xcd * 4 + (seq >> 3);
  int ktdt = seq & 7;
  int kt = ktdt & 3, dt = ktdt >> 2;
  int k0 = kt * 256, d0 = dt * 128;
  int l = t & 63, wv = t >> 6;
  int wk = wv >> 1, wd = wv & 1;
  const ushort* Abase = (ns < 16) ? sT0 : sT1;
  size_t nloc0 = (size_t)(ns & 15) * 1024;
  f32x4 zero = {0.f, 0.f, 0.f, 0.f};
  f32x4 acc[4][4];
#pragma unroll
  for (int i = 0; i < 4; ++i)
#pragma unroll
    for (int j = 0; j < 4; ++j) acc[i][j] = zero;
  float colacc[4] = {0.f, 0.f, 0.f, 0.f};

  int colv = (t & 7) * 8;
  int rbase = t >> 3;
  for (int s = 0; s < 16; ++s) {
#pragma unroll
    for (int p = 0; p < 4; ++p) {
      int row = p * 64 + rbase;
      const uint* ap = (const uint*)(Abase + (size_t)(k0 + row) * NHALF + nloc0 + s * 64 + colv);
      uint4 v; v.x = ap[0]; v.y = ap[1]; v.z = ap[2]; v.w = ap[3];
      *(uint4*)&Abuf[row * 72 + colv] = v;
    }
#pragma unroll
    for (int p = 0; p < 2; ++p) {
      int row = p * 64 + rbase;
      const float* xp = &x[((size_t)ns * DDIM + d0 + row) * 1024 + s * 64 + colv];
      float4 a = *(const float4*)xp;
      float4 b = *(const float4*)(xp + 4);
      union { ushort u[8]; uint4 q; } pk;
      pk.u[0] = f2bf(a.x); pk.u[1] = f2bf(a.y); pk.u[2] = f2bf(a.z); pk.u[3] = f2bf(a.w);
      pk.u[4] = f2bf(b.x); pk.u[5] = f2bf(b.y); pk.u[6] = f2bf(b.z); pk.u[7] = f2bf(b.w);
      *(uint4*)&Bbuf[row * 72 + colv] = pk.q;
    }
    __syncthreads();
    bf16x8 af[4], bfr[4];
#pragma unroll
    for (int nb2 = 0; nb2 < 2; ++nb2) {
#pragma unroll
      for (int sub = 0; sub < 4; ++sub) {
        af[sub] = *(const bf16x8*)&Abuf[(wk * 64 + sub * 16 + (l & 15)) * 72 + nb2 * 32 + (l >> 4) * 8];
        bfr[sub] = *(const bf16x8*)&Bbuf[(wd * 64 + sub * 16 + (l & 15)) * 72 + nb2 * 32 + (l >> 4) * 8];
      }
      if (dt == 0 && wd == 0) {
#pragma unroll
        for (int sub = 0; sub < 4; ++sub)
#pragma unroll
          for (int q = 0; q < 8; ++q)
            colacc[sub] += bf2f((ushort)af[sub][q]);
      }
#pragma unroll
      for (int i = 0; i < 4; ++i)
#pragma unroll
        for (int j = 0; j < 4; ++j)
          acc[i][j] = __builtin_amdgcn_mfma_f32_16x16x32_bf16(af[i], bfr[j], acc[i][j], 0, 0, 0);
    }
    __syncthreads();
  }
  ushort* Pb = P + (size_t)ns * (KCB * DDIM);
#pragma unroll
  for (int i = 0; i < 4; ++i)
#pragma unroll
    for (int j = 0; j < 4; ++j) {
#pragma unroll
      for (int r = 0; r < 4; ++r) {
        int k = k0 + wk * 64 + i * 16 + (l >> 4) * 4 + r;
        int d = d0 + wd * 64 + j * 16 + (l & 15);
        Pb[(size_t)k * DDIM + d] = f2bf(acc[i][j][r]);
      }
    }
  if (dt == 0 && wd == 0) {
#pragma unroll
    for (int sub = 0; sub < 4; ++sub) {
      float s = colacc[sub];
      s += __shfl_xor(s, 16);
      s += __shfl_xor(s, 32);
      if (l < 16) atomicAdd(&colsum[k0 + wk * 64 + sub * 16 + l], s);
    }
  }
}

// ---------------- loss & perplexity only ----------------
__global__ void k_final1(const float* __restrict__ hcnt, const float* __restrict__ bent,
                         float* __restrict__ out) {
  __shared__ float red[1024];
  int t = threadIdx.x;
  float s = 0.f;
  for (int i = t; i < 4352; i += 1024) s += bent[i];
  red[t] = s;
  __syncthreads();
  for (int off = 512; off > 0; off >>= 1) { if (t < off) red[t] += red[t + off]; __syncthreads(); }
  if (t == 0) out[O_LOSS] = 0.25f * (red[0] / 32768.0f);
  __syncthreads();
  float avg = hcnt[t] * (1.0f / 32768.0f);
  red[t] = avg * logf(avg + 1e-10f);
  __syncthreads();
  for (int off = 512; off > 0; off >>= 1) { if (t < off) red[t] += red[t + off]; __syncthreads(); }
  if (t == 0) out[O_PERP] = expf(-red[0]);
}

// ---------------- reduce bf16 P partials + ncnt + new_ema_weight & new_embedding ----------------
// grid 256 x 256 thr; each thread handles 4 consecutive elements (uint2 per slice).
__global__ void k_reduce_final2(const ushort* __restrict__ P,
                                const float* __restrict__ ema_w,
                                const float* __restrict__ ema_count,
                                const float* __restrict__ colsum,
                                float* __restrict__ outNC,
                                float* __restrict__ outEW,
                                float* __restrict__ outEMB) {
  int i4 = (blockIdx.x * 256 + threadIdx.x) * 4;
  int k = i4 >> 8;
  float nc = ema_count[k] * 0.99f + colsum[k] * 0.01f;
  nc = (nc + 1e-5f) / (32768.0f + 1024.0f * 1e-5f) * 32768.0f;
  if ((i4 & 255) == 0) outNC[k] = nc;
  float s0 = 0.f, s1 = 0.f, s2 = 0.f, s3 = 0.f;
#pragma unroll
  for (int ns = 0; ns < 32; ++ns) {
    uint2 v = *(const uint2*)&P[(size_t)ns * (KCB * DDIM) + i4];
    s0 += bf2f((ushort)(v.x & 0xffffu)); s1 += bf2f((ushort)(v.x >> 16));
    s2 += bf2f((ushort)(v.y & 0xffffu)); s3 += bf2f((ushort)(v.y >> 16));
  }
  float4 ew4 = *(const float4*)&ema_w[i4];
  float invnc = 1.0f / nc;
  float e0 = ew4.x * 0.99f + s0 * 0.01f;
  float e1 = ew4.y * 0.99f + s1 * 0.01f;
  float e2 = ew4.z * 0.99f + s2 * 0.01f;
  float e3 = ew4.w * 0.99f + s3 * 0.01f;
  float4 ewo = {e0, e1, e2, e3};
  float4 emo = {e0 * invnc, e1 * invnc, e2 * invnc, e3 * invnc};
  *(float4*)&outEW[i4] = ewo;
  *(float4*)&outEMB[i4] = emo;
}

// ---------------- one-hot encodings (overwrites E scratch, last) ----------------
__global__ void k_onehot(const int* __restrict__ idxArr, float* __restrict__ E) {
  int gid = blockIdx.x * 256 + threadIdx.x;
  int n = gid >> 8;
  int k4 = (gid & 255) * 4;
  int id = idxArr[n];
  float2* E2 = (float2*)E;
  size_t base = ((size_t)n * KCB + k4) >> 1;
  float2 vA = {(float)(k4 == id), (float)(k4 + 1 == id)};
  float2 vB = {(float)(k4 + 2 == id), (float)(k4 + 3 == id)};
  E2[base] = vA;
  E2[base + 1] = vB;
}

extern "C" void kernel_launch(void* const* d_in, const int* in_sizes, int n_in,
                              void* d_out, int out_size, void* d_ws, size_t ws_size,
                              hipStream_t stream) {
  const float* x = (const float*)d_in[0];
  const float* w = (const float*)d_in[1];
  const float* ema_count = (const float*)d_in[2];
  const float* ema_w = (const float*)d_in[3];
  const float* g = (const float*)d_in[4];
  float* out = (float*)d_out;
  float* ws = (float*)d_ws;

  float* wsq    = ws + W_WSQ;
  float* xsq    = ws + W_XSQ;
  int*   idxArr = (int*)(ws + W_IDX);
  float* colsum = ws + W_COL;
  float* hcnt   = ws + W_HCNT;
  float* bent   = ws + W_BENT;
  int*   top2i  = (int*)(ws + W_T2I);
  ushort* WB    = (ushort*)(ws + W_WB);
  float* Mrow   = ws + W_MROW;
  float* Irow   = ws + W_IROW;

  float* outQ = out + O_Q;
  float* outE = out + O_ENC;

  ushort* XS3    = (ushort*)(outE + E_XS3);     // 16B-aligned
  float*  Sslot  = outE + E_S;
  ushort* Pbf    = (ushort*)Sslot;              // bf16 P partials alias Sslot head (16.8 MB)
  ushort* softT1 = (ushort*)(outE + E_XS3);     // overwrites XS3 after refine
  ushort* softT0 = (ushort*)outQ;               // Q region (4B-aligned: uint ops only)

  k_init<<<4, 256, 0, stream>>>(hcnt, colsum);
  k_wsplit<<<256, 256, 0, stream>>>(w, wsq, WB);
  k_xsplit<<<1024, 256, 0, stream>>>(x, XS3, xsq);
  // ---- half 0 (rows 0..16383): fused stats + softT0 ----
  k_gemm1t<<<1024, 256, 0, stream>>>(XS3, WB, wsq, xsq, Sslot);
  k_rowfuse<<<256, 512, 0, stream>>>(Sslot, g, bent, top2i, softT0);
  // ---- half 1 (rows 16384..32767): split path (refine needs XS3 before softT1) ----
  k_gemm1t<<<1024, 256, 0, stream>>>(XS3 + (size_t)NHALF * 768, WB,
                                     wsq, xsq + NHALF, Sslot);
  k_rowstat<<<4096, 256, 0, stream>>>(Sslot, g + (size_t)NHALF * 1024,
                                      Mrow, Irow, bent + 256, top2i + NHALF * 2);
  k_refine<<<512, 256, 0, stream>>>(XS3, w, wsq, xsq, g, top2i, idxArr, hcnt);
  k_rowwrite<<<256, 512, 0, stream>>>(Sslot, Mrow, Irow, softT1);  // over XS3
  k_gemm2_mfma<<<256, 512, 0, stream>>>(softT0, softT1, x, Pbf, colsum);  // P bf16 -> Sslot head
  k_reduce_final2<<<256, 256, 0, stream>>>(Pbf, ema_w, ema_count, colsum,
                                           out + O_NCNT, out + O_EMAW, out + O_EMB);
  k_final1<<<1, 1024, 0, stream>>>(hcnt, bent, out);
  k_quant<<<128, 256, 0, stream>>>(w, idxArr, outQ);       // overwrites softT0
  k_onehot<<<32768, 256, 0, stream>>>(idxArr, outE);       // overwrites all E scratch
}